// Round 2
// baseline (1569.339 us; speedup 1.0000x reference)
//
#include <hip/hip_runtime.h>
#include <cstdint>

typedef __bf16 bf16x8 __attribute__((ext_vector_type(8)));
typedef __bf16 bf16x4 __attribute__((ext_vector_type(4)));
typedef float  f32x4  __attribute__((ext_vector_type(4)));

#define VOCAB 32000
#define EMB   512
#define HID   1024
#define LAT   512
#define BATCH 32
#define TSTEP 127          // T-1
#define MROWS 4064         // TSTEP*BATCH
#define MPAD  4096
#define G4    4096         // 4*HID

__device__ __forceinline__ float sigf(float x){ return 1.0f / (1.0f + __expf(-x)); }
__device__ __forceinline__ float tanhfast(float x){
    float ax = fabsf(x);
    float e  = __expf(-2.0f * ax);      // e in (0,1], no overflow
    float t  = (1.0f - e) / (1.0f + e);
    return copysignf(t, x);
}

// ---------------------------------------------------------------------------
// fp32 -> bf16 bulk convert (W_hh)
// ---------------------------------------------------------------------------
__global__ __launch_bounds__(256) void cvt_kernel(
    const float* __restrict__ in, __bf16* __restrict__ out, int n4)
{
    int i = blockIdx.x * 256 + threadIdx.x;
    if (i < n4){
        float4 v = ((const float4*)in)[i];
        bf16x4 o = { (__bf16)v.x, (__bf16)v.y, (__bf16)v.z, (__bf16)v.w };
        ((bf16x4*)out)[i] = o;
    }
}

// ---------------------------------------------------------------------------
// K0: h0 = latent @ W_lh^T + b_lh (fp32 in, bf16 h out); zero Hall pad + cbuf
// ---------------------------------------------------------------------------
__global__ __launch_bounds__(256) void init_kernel(
    const float* __restrict__ latent,
    const float* __restrict__ Wlh,
    const float* __restrict__ blh,
    __bf16* __restrict__ h0,
    __bf16* __restrict__ Hall,
    float*  __restrict__ cbuf)
{
    int id = blockIdx.x * 256 + threadIdx.x;   // 128 blocks -> 32768 = BATCH*HID
    int b = id >> 10, j = id & 1023;
    float s = blh[j];
    const float4* lr = (const float4*)(latent + (size_t)b * LAT);
    const float4* wr = (const float4*)(Wlh + (size_t)j * LAT);
    for (int k = 0; k < LAT / 4; ++k){
        float4 a = lr[k], w = wr[k];
        s += a.x * w.x + a.y * w.y + a.z * w.z + a.w * w.w;
    }
    h0[id] = (__bf16)s;                         // h0[b][j]
    Hall[(size_t)MROWS * HID + id] = (__bf16)0.0f;  // zero pad rows 4064..4095
    cbuf[id] = 0.0f;                            // c = 0
}

// ---------------------------------------------------------------------------
// NT GEMM: C[M,N] = A(MxK) * B(NxK)^T  (128x128 tile, BK=32, 4 waves)
// A/B converted fp32->bf16 during reg-staging into LDS.
// EPI=0: A = gathered emb rows (fp32), C = fp32 xg (+b_ih+b_hh)
// EPI=1: A = Hall (bf16),             C = fp32 logits scattered (+b_out)
// ---------------------------------------------------------------------------
template<int EPI>
__global__ __launch_bounds__(256) void gemm_nt(
    const float*  __restrict__ Af,
    const __bf16* __restrict__ Ab,
    const float*  __restrict__ Bf,
    const int*    __restrict__ tok,
    float*        __restrict__ C,
    const float*  __restrict__ bias1,
    const float*  __restrict__ bias2,
    int K)
{
    __shared__ __bf16 As[2][128 * 32];
    __shared__ __bf16 Bs[2][128 * 32];

    const int tid  = threadIdx.x;
    const int wid  = tid >> 6, lane = tid & 63;
    const int tile_n = blockIdx.x, tile_m = blockIdx.y;
    const int wr = wid >> 1, wc = wid & 1;

    f32x4 acc[4][4] = {};

    auto stage = [&](int kt, int buf){
        #pragma unroll
        for (int j = 0; j < 2; ++j){
            const int slot = tid + j * 256;       // [0,512)
            const int row  = slot >> 2;           // [0,128)
            const int kb   = kt * 32 + (slot & 3) * 8;
            // B: fp32 -> bf16
            {
                const int brow = tile_n * 128 + row;
                const float4* p = (const float4*)(Bf + (size_t)brow * K + kb);
                float4 u = p[0], v = p[1];
                bf16x8 w = { (__bf16)u.x, (__bf16)u.y, (__bf16)u.z, (__bf16)u.w,
                             (__bf16)v.x, (__bf16)v.y, (__bf16)v.z, (__bf16)v.w };
                *(bf16x8*)&Bs[buf][row * 32 + (slot & 3) * 8] = w;
            }
            // A
            if constexpr (EPI == 0){
                int r = tile_m * 128 + row;
                int rc = (r < MROWS) ? r : (MROWS - 1);
                int token = tok[(rc & 31) * 128 + (rc >> 5)];   // tokens[b][t]
                const float4* p = (const float4*)(Af + (size_t)token * K + kb);
                float4 u = p[0], v = p[1];
                bf16x8 w = { (__bf16)u.x, (__bf16)u.y, (__bf16)u.z, (__bf16)u.w,
                             (__bf16)v.x, (__bf16)v.y, (__bf16)v.z, (__bf16)v.w };
                *(bf16x8*)&As[buf][row * 32 + (slot & 3) * 8] = w;
            } else {
                int r = tile_m * 128 + row;       // Hall padded to MPAD rows
                *(bf16x8*)&As[buf][row * 32 + (slot & 3) * 8] =
                    *(const bf16x8*)(Ab + (size_t)r * K + kb);
            }
        }
    };

    const int KT = K / 32;
    stage(0, 0);
    for (int kt = 0; kt < KT; ++kt){
        const int buf = kt & 1;
        __syncthreads();                       // staged tile ready; prev compute done
        if (kt + 1 < KT) stage(kt + 1, buf ^ 1);
        const __bf16* Abuf = As[buf];
        const __bf16* Bbuf = Bs[buf];
        const int ar = lane & 15, ko = (lane >> 4) * 8;
        bf16x8 av[4], bv[4];
        #pragma unroll
        for (int m = 0; m < 4; ++m)
            av[m] = *(const bf16x8*)&Abuf[(wr * 64 + m * 16 + ar) * 32 + ko];
        #pragma unroll
        for (int n = 0; n < 4; ++n)
            bv[n] = *(const bf16x8*)&Bbuf[(wc * 64 + n * 16 + ar) * 32 + ko];
        #pragma unroll
        for (int m = 0; m < 4; ++m)
            #pragma unroll
            for (int n = 0; n < 4; ++n)
                acc[m][n] = __builtin_amdgcn_mfma_f32_16x16x32_bf16(av[m], bv[n], acc[m][n], 0, 0, 0);
    }

    const int r0 = tile_m * 128 + wr * 64 + ((lane >> 4) << 2);
    const int c0 = tile_n * 128 + wc * 64 + (lane & 15);
    #pragma unroll
    for (int m = 0; m < 4; ++m){
        #pragma unroll
        for (int n = 0; n < 4; ++n){
            const int col = c0 + n * 16;
            float badd = bias1[col];
            if constexpr (EPI == 0) badd += bias2[col];
            #pragma unroll
            for (int q = 0; q < 4; ++q){
                int row = r0 + m * 16 + q;
                float v = acc[m][n][q] + badd;
                if constexpr (EPI == 0){
                    C[(size_t)row * G4 + col] = v;
                } else {
                    if (row < MROWS){
                        int t = row >> 5, b = row & 31;
                        C[((size_t)b * TSTEP + t) * VOCAB + col] = v;
                    }
                }
            }
        }
    }
}

// ---------------------------------------------------------------------------
// One LSTM step: gates = h@Whh^T (MFMA) + xg;  c,h update;  h -> hW, Hall.
// 128 blocks x 256 thr; block owns 8 hidden units (32 gate cols x 32 batch).
// ---------------------------------------------------------------------------
__global__ __launch_bounds__(256) void step_kernel(
    const float*  __restrict__ xg,
    __bf16*       __restrict__ Hall,
    const __bf16* __restrict__ hR,
    __bf16*       __restrict__ hW,
    const __bf16* __restrict__ Whhb,
    float*        __restrict__ cbuf,
    int t)
{
    __shared__ float lds_g[4 * 4 * 4 * 64];    // [acc][wid][reg][lane] = 16KB
    const int tid = threadIdx.x, wid = tid >> 6, lane = tid & 63;
    const int jb = blockIdx.x * 8;

    // B fragments: W_hh rows for our 32 gate cols, this wave's K-quarter
    bf16x8 bfrag[2][8];
    {
        const int gl = lane & 15, ko = (lane >> 4) * 8;
        #pragma unroll
        for (int nt = 0; nt < 2; ++nt){
            int gg = nt * 16 + gl;                     // type=gg>>3, unit=gg&7
            const __bf16* base =
                Whhb + (size_t)((gg >> 3) * HID + jb + (gg & 7)) * HID + wid * 256 + ko;
            #pragma unroll
            for (int ks = 0; ks < 8; ++ks)
                bfrag[nt][ks] = *(const bf16x8*)(base + ks * 32);
        }
    }

    const __bf16* abase = hR + (size_t)(lane & 15) * HID + wid * 256 + (lane >> 4) * 8;
    f32x4 a00 = {}, a01 = {}, a10 = {}, a11 = {};
    #pragma unroll
    for (int ks = 0; ks < 8; ++ks){
        bf16x8 x0 = *(const bf16x8*)(abase + ks * 32);
        bf16x8 x1 = *(const bf16x8*)(abase + 16 * HID + ks * 32);
        a00 = __builtin_amdgcn_mfma_f32_16x16x32_bf16(x0, bfrag[0][ks], a00, 0, 0, 0);
        a01 = __builtin_amdgcn_mfma_f32_16x16x32_bf16(x0, bfrag[1][ks], a01, 0, 0, 0);
        a10 = __builtin_amdgcn_mfma_f32_16x16x32_bf16(x1, bfrag[0][ks], a10, 0, 0, 0);
        a11 = __builtin_amdgcn_mfma_f32_16x16x32_bf16(x1, bfrag[1][ks], a11, 0, 0, 0);
    }
    #pragma unroll
    for (int q = 0; q < 4; ++q){
        lds_g[((0 * 4 + wid) * 4 + q) * 64 + lane] = a00[q];
        lds_g[((1 * 4 + wid) * 4 + q) * 64 + lane] = a01[q];
        lds_g[((2 * 4 + wid) * 4 + q) * 64 + lane] = a10[q];
        lds_g[((3 * 4 + wid) * 4 + q) * 64 + lane] = a11[q];
    }
    __syncthreads();

    const int b = tid >> 3, u = tid & 7;               // (batch, unit)
    const int mt_u = b >> 4, r_u = b & 15, reg_u = r_u & 3, lb_u = (r_u >> 2) << 4;
    float gate[4];
    #pragma unroll
    for (int ty = 0; ty < 4; ++ty){
        int gg = ty * 8 + u;
        int mtnt = mt_u * 2 + (gg >> 4);
        int li = lb_u | (gg & 15);
        float s = 0.0f;
        #pragma unroll
        for (int w = 0; w < 4; ++w)
            s += lds_g[((mtnt * 4 + w) * 4 + reg_u) * 64 + li];
        gate[ty] = s;
    }
    const size_t xrow = ((size_t)t * BATCH + b) * G4 + jb + u;
    float gi = gate[0] + xg[xrow];
    float gf = gate[1] + xg[xrow + HID];
    float gc = gate[2] + xg[xrow + 2 * HID];
    float go = gate[3] + xg[xrow + 3 * HID];

    const int hidx = b * HID + jb + u;
    float c = cbuf[hidx];
    c = sigf(gf) * c + sigf(gi) * tanhfast(gc);
    float h = sigf(go) * tanhfast(c);
    cbuf[hidx] = c;
    __bf16 h16 = (__bf16)h;
    hW[hidx] = h16;
    Hall[((size_t)t * BATCH + b) * HID + jb + u] = h16;
}

// ---------------------------------------------------------------------------
extern "C" void kernel_launch(void* const* d_in, const int* in_sizes, int n_in,
                              void* d_out, int out_size, void* d_ws, size_t ws_size,
                              hipStream_t stream)
{
    const float* latent = (const float*)d_in[0];
    const int*   tokens = (const int*)d_in[1];
    const float* emb    = (const float*)d_in[2];
    const float* Wlh    = (const float*)d_in[3];
    const float* blh    = (const float*)d_in[4];
    const float* Wih    = (const float*)d_in[5];
    const float* bih    = (const float*)d_in[6];
    const float* Whh    = (const float*)d_in[7];
    const float* bhh    = (const float*)d_in[8];
    const float* Wout   = (const float*)d_in[9];
    const float* bout   = (const float*)d_in[10];
    float* out = (float*)d_out;

    const size_t xg_b   = (size_t)MPAD * G4 * 4;        // 64 MiB fp32 gate preacts
    const size_t hall_b = (size_t)MPAD * HID * 2;       // 8 MiB bf16
    const size_t whh_b  = (size_t)G4 * HID * 2;         // 8 MiB bf16
    const size_t hb_b   = (size_t)2 * BATCH * HID * 2;  // 128 KiB
    const size_t c_b    = (size_t)BATCH * HID * 4;      // 128 KiB

    char* ws = (char*)d_ws;
    float* xg;
    char* rest;
    if (ws_size >= xg_b + hall_b + whh_b + hb_b + c_b){
        xg   = (float*)ws;
        rest = ws + xg_b;
    } else {
        xg   = (float*)d_out;   // 64 MiB scratch at head of 520 MiB out; consumed
        rest = ws;              // before gemm_nt<1> overwrites it
    }
    __bf16* Hall = (__bf16*)rest;
    __bf16* Whhb = (__bf16*)(rest + hall_b);
    __bf16* hA   = (__bf16*)(rest + hall_b + whh_b);
    __bf16* hB   = hA + BATCH * HID;
    float*  cbuf = (float*)(rest + hall_b + whh_b + hb_b);

    cvt_kernel<<<dim3((G4 * HID / 4 + 255) / 256), dim3(256), 0, stream>>>(
        Whh, Whhb, G4 * HID / 4);

    init_kernel<<<dim3(128), dim3(256), 0, stream>>>(latent, Wlh, blh, hA, Hall, cbuf);

    gemm_nt<0><<<dim3(G4 / 128, MPAD / 128), dim3(256), 0, stream>>>(
        emb, (const __bf16*)nullptr, Wih, tokens, xg, bih, bhh, EMB);

    for (int t = 0; t < TSTEP; ++t){
        const __bf16* hR = (t & 1) ? hB : hA;
        __bf16*       hW = (t & 1) ? hA : hB;
        step_kernel<<<dim3(128), dim3(256), 0, stream>>>(xg, Hall, hR, hW, Whhb, cbuf, t);
    }

    gemm_nt<1><<<dim3(VOCAB / 128, MPAD / 128), dim3(256), 0, stream>>>(
        (const float*)nullptr, Hall, Wout, (const int*)nullptr, out, bout,
        (const float*)nullptr, HID);
}